// Round 1
// 448.292 us; speedup vs baseline: 1.5239x; 1.5239x over previous
//
#include <hip/hip_runtime.h>
#include <hip/hip_bf16.h>

// Problem constants
#define Bb 2
#define Ss 2048
#define DMD 2048
#define Hh 32
#define KVh 8
#define HD 64
// GQA groups = H/KV = 4. Inputs/outputs fp32.

using bf16 = __hip_bfloat16;
typedef __attribute__((ext_vector_type(8))) short short8;
typedef __attribute__((ext_vector_type(4))) float floatx4;

__device__ inline float tof(const bf16 x) { return __bfloat162float(x); }
__device__ inline void stor(float* p, float v) { *p = v; }
__device__ inline void stor(bf16* p, float v) { *p = __float2bfloat16(v); }
__device__ inline short bf16bits(float v) {
    union { bf16 h; short s; } cv; cv.h = __float2bfloat16(v); return cv.s;
}

// global->LDS direct copy, 16 B per lane. LDS destination is the wave-uniform
// base; HW adds lane*16. (guide §5: width=16 is the 874-TF m97 staging path)
__device__ inline void gl_lds16(const bf16* g, bf16* l) {
    __builtin_amdgcn_global_load_lds(
        (const __attribute__((address_space(1))) unsigned int*)g,
        (__attribute__((address_space(3))) unsigned int*)l, 16, 0, 0);
}

// ---------------------------------------------------------------------------
// Prep pass 1: fp32 -> bf16 elementwise (8 elems/thread, float4 loads).
// ---------------------------------------------------------------------------
__global__ __launch_bounds__(256) void cvt_bf16_kernel(
    const float* __restrict__ in, bf16* __restrict__ out, int total8)
{
    const int i = blockIdx.x * 256 + threadIdx.x;
    if (i >= total8) return;
    const float4 a = ((const float4*)in)[2 * i];
    const float4 b = ((const float4*)in)[2 * i + 1];
    short8 r;
    r[0] = bf16bits(a.x); r[1] = bf16bits(a.y); r[2] = bf16bits(a.z); r[3] = bf16bits(a.w);
    r[4] = bf16bits(b.x); r[5] = bf16bits(b.y); r[6] = bf16bits(b.z); r[7] = bf16bits(b.w);
    ((short8*)out)[i] = r;
}

// ---------------------------------------------------------------------------
// Prep pass 2: W [K][N] fp32 -> Wt [rowOff+N][K] bf16 (transpose-convert),
// 32x32 LDS tile, 256 threads.
// ---------------------------------------------------------------------------
__global__ __launch_bounds__(256) void cvtT_kernel(
    const float* __restrict__ W, bf16* __restrict__ Wt,
    int N, int K, int rowOff)
{
    __shared__ float t[32][33];
    const int n0 = blockIdx.x * 32;
    const int k0 = blockIdx.y * 32;
    const int tx = threadIdx.x & 31, ty = threadIdx.x >> 5;   // ty 0..7
    #pragma unroll
    for (int r = 0; r < 32; r += 8)
        t[ty + r][tx] = W[(size_t)(k0 + ty + r) * N + n0 + tx];
    __syncthreads();
    #pragma unroll
    for (int r = 0; r < 32; r += 8)
        Wt[(size_t)(rowOff + n0 + ty + r) * K + k0 + tx] =
            __float2bfloat16(t[tx][ty + r]);
}

// ---------------------------------------------------------------------------
// MFMA GEMM, m97 structure: A [M][K] bf16 row-major, Bt [N][K] bf16 K-major.
// 128x128 tile, BK=32, 4 waves x (4x4 16x16x32 tiles), global_load_lds
// width-16 staging into linear [128][32] LDS tiles, 2-barrier loop.
// EPI 0: fused QKV scatter  (cols [0,2048)->Yq, [2048,2560)->Yk,
//        [2560,3072)->Yv transposed [b][kvh][d][s] with +bias)
// EPI 1: fp32 out + bias (O projection)
// ---------------------------------------------------------------------------
template <int EPI>
__global__ __launch_bounds__(256) void gemm_bt(
    const bf16* __restrict__ A, const bf16* __restrict__ Bt,
    const float* __restrict__ bias,
    bf16* __restrict__ Yq, bf16* __restrict__ Yk, bf16* __restrict__ Yv,
    float* __restrict__ Yo, int M, int N, int K)
{
    __shared__ bf16 As[128 * 32];   // [m][k] row-major, chunk ch <-> bytes ch*16
    __shared__ bf16 Bs[128 * 32];   // [n][k] row-major

    const int tid  = threadIdx.x;
    const int wave = tid >> 6, lane = tid & 63;
    const int lid  = lane & 15, quad = lane >> 4;
    const int wr = (wave >> 1) * 64, wc = (wave & 1) * 64;
    const size_t bm = (size_t)blockIdx.y * 128, bn = (size_t)blockIdx.x * 128;

    floatx4 acc[4][4];
    #pragma unroll
    for (int i = 0; i < 4; ++i)
        #pragma unroll
        for (int j = 0; j < 4; ++j)
            acc[i][j] = (floatx4){0.f, 0.f, 0.f, 0.f};

    for (int k0 = 0; k0 < K; k0 += 32) {
        // stage A-tile and B-tile: 512 16B-chunks each; wave covers 128
        // chunks (2 issues). chunk c: row = c>>2, k-col = (c&3)*8.
        #pragma unroll
        for (int i = 0; i < 2; ++i) {
            const int c   = wave * 128 + i * 64 + lane;
            const int row = c >> 2, col = (c & 3) * 8;
            gl_lds16(A  + (bm + row) * (size_t)K + k0 + col,
                     &As[(wave * 128 + i * 64) * 8]);
            gl_lds16(Bt + (bn + row) * (size_t)K + k0 + col,
                     &Bs[(wave * 128 + i * 64) * 8]);
        }
        __syncthreads();

        short8 af[4], bfr[4];
        #pragma unroll
        for (int i = 0; i < 4; ++i)
            af[i] = *(const short8*)&As[(wr + i * 16 + lid) * 32 + quad * 8];
        #pragma unroll
        for (int j = 0; j < 4; ++j)
            bfr[j] = *(const short8*)&Bs[(wc + j * 16 + lid) * 32 + quad * 8];
        #pragma unroll
        for (int i = 0; i < 4; ++i)
            #pragma unroll
            for (int j = 0; j < 4; ++j)
                acc[i][j] = __builtin_amdgcn_mfma_f32_16x16x32_bf16(
                    af[i], bfr[j], acc[i][j], 0, 0, 0);
        __syncthreads();
    }

    #pragma unroll
    for (int i = 0; i < 4; ++i) {
        const int gm0 = (int)bm + wr + i * 16 + quad * 4;
        #pragma unroll
        for (int j = 0; j < 4; ++j) {
            const int gn = (int)bn + wc + j * 16 + lid;
            #pragma unroll
            for (int r = 0; r < 4; ++r) {
                float v = acc[i][j][r];
                const int gm = gm0 + r;
                if (EPI == 0) {
                    if (gn < Hh * HD) {
                        stor(&Yq[(size_t)gm * (Hh * HD) + gn], v);
                    } else if (gn < Hh * HD + KVh * HD) {
                        stor(&Yk[(size_t)gm * (KVh * HD) + (gn - Hh * HD)], v);
                    } else {
                        const int c = gn - (Hh * HD + KVh * HD);
                        v += bias[c];
                        const int kvh = c >> 6, dd = c & 63;
                        const int bbi = gm >> 11, s = gm & (Ss - 1);
                        stor(&Yv[(((size_t)bbi * KVh + kvh) * HD + dd) * Ss + s], v);
                    }
                } else {
                    Yo[(size_t)gm * N + gn] = v + bias[gn];
                }
            }
        }
    }
}

// ---------------------------------------------------------------------------
// In-place RoPE on bf16 buf laid out [B*S][nheads][64]; fp32 cos/sin.
// scale: extra output multiplier (1/sqrt(HD) folded into Q).
// ---------------------------------------------------------------------------
__global__ void rope_kernel(bf16* __restrict__ buf,
                            const float* __restrict__ cosb,
                            const float* __restrict__ sinb,
                            int nheads, int total, float scale)
{
    int idx = blockIdx.x * blockDim.x + threadIdx.x;
    if (idx >= total) return;
    int d = idx & 31;
    int h = (idx >> 5) % nheads;
    int bs = idx / (32 * nheads);
    bf16* row = buf + ((size_t)bs * nheads + h) * HD;
    float x1 = tof(row[d]), x2 = tof(row[d + 32]);
    float c1 = cosb[(size_t)bs * HD + d];
    float s1 = sinb[(size_t)bs * HD + d];
    float c2 = cosb[(size_t)bs * HD + d + 32];
    float s2 = sinb[(size_t)bs * HD + d + 32];
    stor(&row[d],      (x1 * c1 - x2 * s1) * scale);
    stor(&row[d + 32], (x2 * c2 + x1 * s2) * scale);
}

// ---------------------------------------------------------------------------
// MFMA flash attention with cooperative LDS staging (unchanged this round).
// ---------------------------------------------------------------------------
__global__ __launch_bounds__(256) void fattn_kernel(
    bf16* __restrict__ QO, const bf16* __restrict__ Kb,
    const bf16* __restrict__ Vt, const int* __restrict__ mask)
{
    const int qt = (Ss / 64 - 1) - blockIdx.x;   // heavy tiles first
    const int h  = blockIdx.y;
    const int b  = blockIdx.z;
    const int kvh = h >> 2;

    const int tid  = threadIdx.x;
    const int wave = tid >> 6;
    const int lane = tid & 63;
    const int lid  = lane & 15;
    const int quad = lane >> 4;

    __shared__ short Ks[8][512];        // [nt*2+unit][lane*8] 16B chunks
    __shared__ short Vs[8][512];
    __shared__ short pLds[4][16][72];   // per-wave private P transpose
    __shared__ int   sMask[64];

    const int m0 = qt * 64 + wave * 16;

    // Q fragments (A-layout; pre-scaled by 1/8 in rope)
    const bf16* qbase = QO + ((size_t)(b * Ss + m0 + lid) * Hh + h) * HD + quad * 8;
    const short8 qf0 = *(const short8*)(qbase);
    const short8 qf1 = *(const short8*)(qbase + 32);

    // Staging bases (thread covers units ntu=wave and ntu=wave+4, chunk=lane)
    const size_t kRowStride = (size_t)KVh * HD;         // 512 elems
    const bf16* kTileBase = Kb + ((size_t)b * Ss) * kRowStride + (size_t)kvh * HD;
    const bf16* vHeadBase = Vt + ((size_t)(b * KVh + kvh) * HD) * Ss;

    floatx4 o[4];
    float l_part[4];
    #pragma unroll
    for (int nt = 0; nt < 4; ++nt) o[nt] = (floatx4){0.f, 0.f, 0.f, 0.f};
    #pragma unroll
    for (int r = 0; r < 4; ++r) l_part[r] = 0.f;

    for (int kt = 0; kt <= qt; ++kt) {
        const int k0 = kt * 64;

        // ---- cooperative staging: K-tile + V-tile (16 KB) + mask ----
        #pragma unroll
        for (int rep = 0; rep < 2; ++rep) {
            const int ntu  = wave + rep * 4;
            const int nt   = ntu >> 1;
            const int unit = ntu & 1;
            const bf16* gk = kTileBase + (size_t)(k0 + nt * 16 + lid) * kRowStride
                           + unit * 32 + quad * 8;
            *(short8*)&Ks[ntu][lane * 8] = *(const short8*)gk;
            const bf16* gv = vHeadBase + (size_t)(nt * 16 + lid) * Ss
                           + k0 + unit * 32 + quad * 8;
            *(short8*)&Vs[ntu][lane * 8] = *(const short8*)gv;
        }
        if (tid < 64) sMask[tid] = mask[b * Ss + k0 + tid];
        __syncthreads();

        // ---- S = Q K^T (LDS fragments, lane-linear) ----
        floatx4 s[4];
        #pragma unroll
        for (int nt = 0; nt < 4; ++nt) {
            const short8 kb0 = *(const short8*)&Ks[nt * 2][lane * 8];
            const short8 kb1 = *(const short8*)&Ks[nt * 2 + 1][lane * 8];
            floatx4 c = (floatx4){0.f, 0.f, 0.f, 0.f};
            c = __builtin_amdgcn_mfma_f32_16x16x32_bf16(qf0, kb0, c, 0, 0, 0);
            c = __builtin_amdgcn_mfma_f32_16x16x32_bf16(qf1, kb1, c, 0, 0, 0);
            s[nt] = c;
        }

        // ---- mask + exp; per-lane row-sum partials ----
        #pragma unroll
        for (int nt = 0; nt < 4; ++nt) {
            const int col = k0 + nt * 16 + lid;
            const int mk = sMask[nt * 16 + lid];
            #pragma unroll
            for (int r = 0; r < 4; ++r) {
                const int mrow = m0 + quad * 4 + r;
                const float p = (mk == 0 || col > mrow) ? 0.f : __expf(s[nt][r]);
                s[nt][r] = p;
                l_part[r] += p;
            }
        }

        // ---- P: C-layout -> A-layout via per-wave private LDS ----
        #pragma unroll
        for (int nt = 0; nt < 4; ++nt)
            #pragma unroll
            for (int r = 0; r < 4; ++r)
                pLds[wave][quad * 4 + r][nt * 16 + lid] = bf16bits(s[nt][r]);
        const short8 pf0 = *(const short8*)&pLds[wave][lid][quad * 8];
        const short8 pf1 = *(const short8*)&pLds[wave][lid][32 + quad * 8];

        // ---- O += P V (LDS fragments) ----
        #pragma unroll
        for (int nt = 0; nt < 4; ++nt) {
            const short8 vb0 = *(const short8*)&Vs[nt * 2][lane * 8];
            const short8 vb1 = *(const short8*)&Vs[nt * 2 + 1][lane * 8];
            floatx4 c = o[nt];
            c = __builtin_amdgcn_mfma_f32_16x16x32_bf16(pf0, vb0, c, 0, 0, 0);
            c = __builtin_amdgcn_mfma_f32_16x16x32_bf16(pf1, vb1, c, 0, 0, 0);
            o[nt] = c;
        }
        __syncthreads();   // protect Ks/Vs before next staging
    }

    // ---- epilogue: reduce l across the 16 key-lanes, normalize, store ----
    #pragma unroll
    for (int r = 0; r < 4; ++r) {
        float rs = l_part[r];
        rs += __shfl_xor(rs, 1);
        rs += __shfl_xor(rs, 2);
        rs += __shfl_xor(rs, 4);
        rs += __shfl_xor(rs, 8);
        const float inv = 1.f / rs;
        const int m = m0 + quad * 4 + r;
        bf16* orow = QO + ((size_t)(b * Ss + m) * Hh + h) * HD;
        #pragma unroll
        for (int nt = 0; nt < 4; ++nt)
            stor(&orow[nt * 16 + lid], o[nt][r] * inv);
    }
}

// ---------------------------------------------------------------------------
extern "C" void kernel_launch(void* const* d_in, const int* in_sizes, int n_in,
                              void* d_out, int out_size, void* d_ws, size_t ws_size,
                              hipStream_t stream)
{
    const float* hs   = (const float*)d_in[0];
    const int*   mask = (const int*)d_in[1];
    const float* cosb = (const float*)d_in[2];
    const float* sinb = (const float*)d_in[3];
    const float* Wq   = (const float*)d_in[4];
    const float* Wk   = (const float*)d_in[5];
    const float* Wv   = (const float*)d_in[6];
    const float* bv   = (const float*)d_in[7];
    const float* Wo   = (const float*)d_in[8];
    const float* bo   = (const float*)d_in[9];
    float* out = (float*)d_out;

    const int M = Bb * Ss;  // 4096

    // Workspace (37.75 MB): QO bf16 [M][2048] (16.8 MB) + Wqkv_t bf16
    // [3072][2048] (12.6 MB) + Wo_t bf16 [2048][2048] (8.4 MB).
    bf16* QO    = (bf16*)d_ws;
    bf16* Wqkvt = QO + (size_t)M * (Hh * HD);
    bf16* Wot   = Wqkvt + (size_t)3072 * DMD;

    // d_out scratch (25.2 MB of 33.5 MB): Kb, Vt (front), Abf (middle).
    // All three are dead before the O-projection overwrites d_out.
    bf16* Kb  = (bf16*)d_out;
    bf16* Vt  = Kb + (size_t)M * (KVh * HD);
    bf16* Abf = Vt + (size_t)M * (KVh * HD);

    dim3 blk(256);

    // Prep: hs -> bf16; weights -> K-major bf16 (Wq|Wk|Wv concatenated).
    const int total8 = M * DMD / 8;
    cvt_bf16_kernel<<<(total8 + 255) / 256, blk, 0, stream>>>(hs, Abf, total8);
    cvtT_kernel<<<dim3((Hh * HD) / 32, DMD / 32), blk, 0, stream>>>(
        Wq, Wqkvt, Hh * HD, DMD, 0);
    cvtT_kernel<<<dim3((KVh * HD) / 32, DMD / 32), blk, 0, stream>>>(
        Wk, Wqkvt, KVh * HD, DMD, Hh * HD);
    cvtT_kernel<<<dim3((KVh * HD) / 32, DMD / 32), blk, 0, stream>>>(
        Wv, Wqkvt, KVh * HD, DMD, Hh * HD + KVh * HD);
    cvtT_kernel<<<dim3(DMD / 32, DMD / 32), blk, 0, stream>>>(
        Wo, Wot, DMD, DMD, 0);

    // Fused QKV projection (bf16 in, bf16 staged out; V transposed +bias).
    gemm_bt<0><<<dim3(3072 / 128, M / 128), blk, 0, stream>>>(
        Abf, Wqkvt, bv, QO, Kb, Vt, nullptr, M, 3072, DMD);

    // RoPE (in place; Q gets the 1/sqrt(HD) softmax scale folded in)
    int totq = M * Hh * 32, totk = M * KVh * 32;
    rope_kernel<<<(totq + 255) / 256, blk, 0, stream>>>(QO, cosb, sinb, Hh, totq, 0.125f);
    rope_kernel<<<(totk + 255) / 256, blk, 0, stream>>>(Kb, cosb, sinb, KVh, totk, 1.0f);

    // Flash attention (O overwrites Q in place)
    fattn_kernel<<<dim3(Ss / 64, Hh, Bb), blk, 0, stream>>>(QO, Kb, Vt, mask);

    // Output projection (+bias, fp32 out)
    gemm_bt<1><<<dim3(DMD / 128, M / 128), blk, 0, stream>>>(
        QO, Wot, bo, nullptr, nullptr, nullptr, out, M, DMD, DMD);
}

// Round 2
// 436.520 us; speedup vs baseline: 1.5650x; 1.0270x over previous
//
#include <hip/hip_runtime.h>
#include <hip/hip_bf16.h>

// Problem constants
#define Bb 2
#define Ss 2048
#define DMD 2048
#define Hh 32
#define KVh 8
#define HD 64
// GQA groups = H/KV = 4. Inputs/outputs fp32.

using bf16 = __hip_bfloat16;
typedef __attribute__((ext_vector_type(8))) short short8;
typedef __attribute__((ext_vector_type(4))) float floatx4;

__device__ inline float tof(const bf16 x) { return __bfloat162float(x); }
__device__ inline void stor(float* p, float v) { *p = v; }
__device__ inline void stor(bf16* p, float v) { *p = __float2bfloat16(v); }
__device__ inline short bf16bits(float v) {
    union { bf16 h; short s; } cv; cv.h = __float2bfloat16(v); return cv.s;
}

// global->LDS direct copy, 16 B per lane. LDS destination is the wave-uniform
// base; HW adds lane*16. (guide §5: width=16 is the 874-TF m97 staging path)
__device__ inline void gl_lds16(const bf16* g, bf16* l) {
    __builtin_amdgcn_global_load_lds(
        (const __attribute__((address_space(1))) unsigned int*)g,
        (__attribute__((address_space(3))) unsigned int*)l, 16, 0, 0);
}

// ---------------------------------------------------------------------------
// Prep pass 1: fp32 -> bf16 elementwise (8 elems/thread, float4 loads).
// ---------------------------------------------------------------------------
__global__ __launch_bounds__(256) void cvt_bf16_kernel(
    const float* __restrict__ in, bf16* __restrict__ out, int total8)
{
    const int i = blockIdx.x * 256 + threadIdx.x;
    if (i >= total8) return;
    const float4 a = ((const float4*)in)[2 * i];
    const float4 b = ((const float4*)in)[2 * i + 1];
    short8 r;
    r[0] = bf16bits(a.x); r[1] = bf16bits(a.y); r[2] = bf16bits(a.z); r[3] = bf16bits(a.w);
    r[4] = bf16bits(b.x); r[5] = bf16bits(b.y); r[6] = bf16bits(b.z); r[7] = bf16bits(b.w);
    ((short8*)out)[i] = r;
}

// ---------------------------------------------------------------------------
// Prep pass 2: W [K][N] fp32 -> Wt [rowOff+N][K] bf16 (transpose-convert),
// 32x32 LDS tile, 256 threads.
// ---------------------------------------------------------------------------
__global__ __launch_bounds__(256) void cvtT_kernel(
    const float* __restrict__ W, bf16* __restrict__ Wt,
    int N, int K, int rowOff)
{
    __shared__ float t[32][33];
    const int n0 = blockIdx.x * 32;
    const int k0 = blockIdx.y * 32;
    const int tx = threadIdx.x & 31, ty = threadIdx.x >> 5;   // ty 0..7
    #pragma unroll
    for (int r = 0; r < 32; r += 8)
        t[ty + r][tx] = W[(size_t)(k0 + ty + r) * N + n0 + tx];
    __syncthreads();
    #pragma unroll
    for (int r = 0; r < 32; r += 8)
        Wt[(size_t)(rowOff + n0 + ty + r) * K + k0 + tx] =
            __float2bfloat16(t[tx][ty + r]);
}

// ---------------------------------------------------------------------------
// MFMA GEMM, m97 structure: A [M][K] bf16 row-major, Bt [N][K] bf16 K-major.
// 128x128 tile, BK=32, 4 waves x (4x4 16x16x32 tiles), global_load_lds
// width-16 staging into linear [128][32] LDS tiles, 2-barrier loop.
// EPI 0: fused QKV scatter  (cols [0,2048)->Yq, [2048,2560)->Yk,
//        [2560,3072)->Yv transposed [b][kvh][d][s] with +bias)
// EPI 1: fp32 out + bias (O projection)
// ---------------------------------------------------------------------------
template <int EPI>
__global__ __launch_bounds__(256) void gemm_bt(
    const bf16* __restrict__ A, const bf16* __restrict__ Bt,
    const float* __restrict__ bias,
    bf16* __restrict__ Yq, bf16* __restrict__ Yk, bf16* __restrict__ Yv,
    float* __restrict__ Yo, int M, int N, int K)
{
    __shared__ bf16 As[128 * 32];   // [m][k] row-major, chunk ch <-> bytes ch*16
    __shared__ bf16 Bs[128 * 32];   // [n][k] row-major

    const int tid  = threadIdx.x;
    const int wave = tid >> 6, lane = tid & 63;
    const int lid  = lane & 15, quad = lane >> 4;
    const int wr = (wave >> 1) * 64, wc = (wave & 1) * 64;
    const size_t bm = (size_t)blockIdx.y * 128, bn = (size_t)blockIdx.x * 128;

    floatx4 acc[4][4];
    #pragma unroll
    for (int i = 0; i < 4; ++i)
        #pragma unroll
        for (int j = 0; j < 4; ++j)
            acc[i][j] = (floatx4){0.f, 0.f, 0.f, 0.f};

    for (int k0 = 0; k0 < K; k0 += 32) {
        // stage A-tile and B-tile: 512 16B-chunks each; wave covers 128
        // chunks (2 issues). chunk c: row = c>>2, k-col = (c&3)*8.
        #pragma unroll
        for (int i = 0; i < 2; ++i) {
            const int c   = wave * 128 + i * 64 + lane;
            const int row = c >> 2, col = (c & 3) * 8;
            gl_lds16(A  + (bm + row) * (size_t)K + k0 + col,
                     &As[(wave * 128 + i * 64) * 8]);
            gl_lds16(Bt + (bn + row) * (size_t)K + k0 + col,
                     &Bs[(wave * 128 + i * 64) * 8]);
        }
        __syncthreads();

        short8 af[4], bfr[4];
        #pragma unroll
        for (int i = 0; i < 4; ++i)
            af[i] = *(const short8*)&As[(wr + i * 16 + lid) * 32 + quad * 8];
        #pragma unroll
        for (int j = 0; j < 4; ++j)
            bfr[j] = *(const short8*)&Bs[(wc + j * 16 + lid) * 32 + quad * 8];
        #pragma unroll
        for (int i = 0; i < 4; ++i)
            #pragma unroll
            for (int j = 0; j < 4; ++j)
                acc[i][j] = __builtin_amdgcn_mfma_f32_16x16x32_bf16(
                    af[i], bfr[j], acc[i][j], 0, 0, 0);
        __syncthreads();
    }

    #pragma unroll
    for (int i = 0; i < 4; ++i) {
        const int gm0 = (int)bm + wr + i * 16 + quad * 4;
        #pragma unroll
        for (int j = 0; j < 4; ++j) {
            const int gn = (int)bn + wc + j * 16 + lid;
            #pragma unroll
            for (int r = 0; r < 4; ++r) {
                float v = acc[i][j][r];
                const int gm = gm0 + r;
                if (EPI == 0) {
                    if (gn < Hh * HD) {
                        stor(&Yq[(size_t)gm * (Hh * HD) + gn], v);
                    } else if (gn < Hh * HD + KVh * HD) {
                        stor(&Yk[(size_t)gm * (KVh * HD) + (gn - Hh * HD)], v);
                    } else {
                        const int c = gn - (Hh * HD + KVh * HD);
                        v += bias[c];
                        const int kvh = c >> 6, dd = c & 63;
                        const int bbi = gm >> 11, s = gm & (Ss - 1);
                        stor(&Yv[(((size_t)bbi * KVh + kvh) * HD + dd) * Ss + s], v);
                    }
                } else {
                    Yo[(size_t)gm * N + gn] = v + bias[gn];
                }
            }
        }
    }
}

// ---------------------------------------------------------------------------
// In-place RoPE on bf16 buf laid out [B*S][nheads][64]; fp32 cos/sin.
// scale: extra output multiplier (1/sqrt(HD) folded into Q).
// ---------------------------------------------------------------------------
__global__ void rope_kernel(bf16* __restrict__ buf,
                            const float* __restrict__ cosb,
                            const float* __restrict__ sinb,
                            int nheads, int total, float scale)
{
    int idx = blockIdx.x * blockDim.x + threadIdx.x;
    if (idx >= total) return;
    int d = idx & 31;
    int h = (idx >> 5) % nheads;
    int bs = idx / (32 * nheads);
    bf16* row = buf + ((size_t)bs * nheads + h) * HD;
    float x1 = tof(row[d]), x2 = tof(row[d + 32]);
    float c1 = cosb[(size_t)bs * HD + d];
    float s1 = sinb[(size_t)bs * HD + d];
    float c2 = cosb[(size_t)bs * HD + d + 32];
    float s2 = sinb[(size_t)bs * HD + d + 32];
    stor(&row[d],      (x1 * c1 - x2 * s1) * scale);
    stor(&row[d + 32], (x2 * c2 + x1 * s2) * scale);
}

// ---------------------------------------------------------------------------
// MFMA flash attention v2: barrier-free, direct-global K/V fragment reads.
// Each wave owns a 32-row q-block (two 16-row MFMA groups) and processes the
// causal-complementary pair (63-pp, pp) sequentially -> every wave does 33+-1
// k-tile iterations (static balance, no tail). K/V fragments are loaded
// per-lane straight from global (identical bytes the old LDS staging
// delivered); the K/V working set per (b,kvh) is 1 MB -> L2-resident, and
// kvh = blockIdx%8 pins it to one XCD's L2. Only per-wave private pLds
// (P transpose C->A layout) remains in LDS; no __syncthreads anywhere.
// ---------------------------------------------------------------------------
__global__ __launch_bounds__(256) void fattn_kernel(
    bf16* __restrict__ QO, const bf16* __restrict__ Kb,
    const bf16* __restrict__ Vt, const int* __restrict__ mask)
{
    const int bid = blockIdx.x;
    const int kvh = bid & 7;            // XCD-local K/V reuse (xcd = bid % 8)
    const int r   = bid >> 3;           // 0..63
    const int pb  = r & 7;              // pair-block
    const int hg  = (r >> 3) & 3;
    const int b   = r >> 5;
    const int h   = kvh * 4 + hg;

    const int tid  = threadIdx.x;
    const int wave = tid >> 6;
    const int lane = tid & 63;
    const int lid  = lane & 15;
    const int quad = lane >> 4;
    const int pp   = pb * 4 + wave;     // pair index 0..31

    __shared__ short pLds[4][2][16][72];   // per-wave private P transpose

    const size_t kStride = (size_t)KVh * HD;  // 512 elems
    const bf16* kBase = Kb + ((size_t)b * Ss) * kStride + (size_t)kvh * HD;
    const bf16* vBase = Vt + ((size_t)(b * KVh + kvh) * HD) * Ss;
    const int*  mBase = mask + b * Ss;

    #pragma unroll 1
    for (int half = 0; half < 2; ++half) {
        const int qw = half ? pp : (63 - pp);   // heavy q-block first
        const int m0 = qw * 32;

        // Q fragments for both 16-row groups (pre-scaled by 1/8 in rope)
        short8 qf0[2], qf1[2];
        #pragma unroll
        for (int g = 0; g < 2; ++g) {
            const bf16* qb = QO + ((size_t)(b * Ss + m0 + g * 16 + lid) * Hh + h) * HD
                           + quad * 8;
            qf0[g] = *(const short8*)(qb);
            qf1[g] = *(const short8*)(qb + 32);
        }

        floatx4 o[2][4];
        float lsum[2][4];
        #pragma unroll
        for (int g = 0; g < 2; ++g) {
            #pragma unroll
            for (int nt = 0; nt < 4; ++nt) o[g][nt] = (floatx4){0.f, 0.f, 0.f, 0.f};
            #pragma unroll
            for (int rr = 0; rr < 4; ++rr) lsum[g][rr] = 0.f;
        }

        const int nkt = (qw >> 1) + 1;
        for (int kt = 0; kt < nkt; ++kt) {
            const int k0 = kt * 64;

            // ---- S = Q K^T; K fragment rows are 128 B contiguous ----
            floatx4 s[2][4];
            #pragma unroll
            for (int nt = 0; nt < 4; ++nt) {
                const bf16* kr = kBase + (size_t)(k0 + nt * 16 + lid) * kStride
                               + quad * 8;
                const short8 kb0 = *(const short8*)(kr);
                const short8 kb1 = *(const short8*)(kr + 32);
                #pragma unroll
                for (int g = 0; g < 2; ++g) {
                    floatx4 c = (floatx4){0.f, 0.f, 0.f, 0.f};
                    c = __builtin_amdgcn_mfma_f32_16x16x32_bf16(qf0[g], kb0, c, 0, 0, 0);
                    c = __builtin_amdgcn_mfma_f32_16x16x32_bf16(qf1[g], kb1, c, 0, 0, 0);
                    s[g][nt] = c;
                }
            }

            // ---- mask + exp; per-lane row-sum partials ----
            #pragma unroll
            for (int nt = 0; nt < 4; ++nt) {
                const int col = k0 + nt * 16 + lid;
                const int mk  = mBase[col];
                #pragma unroll
                for (int g = 0; g < 2; ++g) {
                    const int mr0 = m0 + g * 16 + quad * 4;
                    #pragma unroll
                    for (int rr = 0; rr < 4; ++rr) {
                        const float p = (mk == 0 || col > mr0 + rr)
                                      ? 0.f : __expf(s[g][nt][rr]);
                        s[g][nt][rr] = p;
                        lsum[g][rr] += p;
                    }
                }
            }

            // ---- P: C-layout -> A-layout via per-wave private LDS ----
            #pragma unroll
            for (int g = 0; g < 2; ++g)
                #pragma unroll
                for (int nt = 0; nt < 4; ++nt)
                    #pragma unroll
                    for (int rr = 0; rr < 4; ++rr)
                        pLds[wave][g][quad * 4 + rr][nt * 16 + lid] =
                            bf16bits(s[g][nt][rr]);
            short8 pf0[2], pf1[2];
            #pragma unroll
            for (int g = 0; g < 2; ++g) {
                pf0[g] = *(const short8*)&pLds[wave][g][lid][quad * 8];
                pf1[g] = *(const short8*)&pLds[wave][g][lid][32 + quad * 8];
            }

            // ---- O += P V; Vt rows are contiguous in keys ----
            #pragma unroll
            for (int nt = 0; nt < 4; ++nt) {
                const bf16* vr = vBase + (size_t)(nt * 16 + lid) * Ss + k0
                               + quad * 8;
                const short8 vb0 = *(const short8*)(vr);
                const short8 vb1 = *(const short8*)(vr + 32);
                #pragma unroll
                for (int g = 0; g < 2; ++g) {
                    o[g][nt] = __builtin_amdgcn_mfma_f32_16x16x32_bf16(
                        pf0[g], vb0, o[g][nt], 0, 0, 0);
                    o[g][nt] = __builtin_amdgcn_mfma_f32_16x16x32_bf16(
                        pf1[g], vb1, o[g][nt], 0, 0, 0);
                }
            }
        }

        // ---- epilogue: reduce l across the 16 key-lanes, normalize, store ----
        #pragma unroll
        for (int g = 0; g < 2; ++g)
            #pragma unroll
            for (int rr = 0; rr < 4; ++rr) {
                float rs = lsum[g][rr];
                rs += __shfl_xor(rs, 1);
                rs += __shfl_xor(rs, 2);
                rs += __shfl_xor(rs, 4);
                rs += __shfl_xor(rs, 8);
                const float inv = 1.f / rs;
                const int m = m0 + g * 16 + quad * 4 + rr;
                bf16* orow = QO + ((size_t)(b * Ss + m) * Hh + h) * HD;
                #pragma unroll
                for (int nt = 0; nt < 4; ++nt)
                    stor(&orow[nt * 16 + lid], o[g][nt][rr] * inv);
            }
    }
}

// ---------------------------------------------------------------------------
extern "C" void kernel_launch(void* const* d_in, const int* in_sizes, int n_in,
                              void* d_out, int out_size, void* d_ws, size_t ws_size,
                              hipStream_t stream)
{
    const float* hs   = (const float*)d_in[0];
    const int*   mask = (const int*)d_in[1];
    const float* cosb = (const float*)d_in[2];
    const float* sinb = (const float*)d_in[3];
    const float* Wq   = (const float*)d_in[4];
    const float* Wk   = (const float*)d_in[5];
    const float* Wv   = (const float*)d_in[6];
    const float* bv   = (const float*)d_in[7];
    const float* Wo   = (const float*)d_in[8];
    const float* bo   = (const float*)d_in[9];
    float* out = (float*)d_out;

    const int M = Bb * Ss;  // 4096

    // Workspace (37.75 MB): QO bf16 [M][2048] (16.8 MB) + Wqkv_t bf16
    // [3072][2048] (12.6 MB) + Wo_t bf16 [2048][2048] (8.4 MB).
    bf16* QO    = (bf16*)d_ws;
    bf16* Wqkvt = QO + (size_t)M * (Hh * HD);
    bf16* Wot   = Wqkvt + (size_t)3072 * DMD;

    // d_out scratch (25.2 MB of 33.5 MB): Kb, Vt (front), Abf (middle).
    // All three are dead before the O-projection overwrites d_out.
    bf16* Kb  = (bf16*)d_out;
    bf16* Vt  = Kb + (size_t)M * (KVh * HD);
    bf16* Abf = Vt + (size_t)M * (KVh * HD);

    dim3 blk(256);

    // Prep: hs -> bf16; weights -> K-major bf16 (Wq|Wk|Wv concatenated).
    const int total8 = M * DMD / 8;
    cvt_bf16_kernel<<<(total8 + 255) / 256, blk, 0, stream>>>(hs, Abf, total8);
    cvtT_kernel<<<dim3((Hh * HD) / 32, DMD / 32), blk, 0, stream>>>(
        Wq, Wqkvt, Hh * HD, DMD, 0);
    cvtT_kernel<<<dim3((KVh * HD) / 32, DMD / 32), blk, 0, stream>>>(
        Wk, Wqkvt, KVh * HD, DMD, Hh * HD);
    cvtT_kernel<<<dim3((KVh * HD) / 32, DMD / 32), blk, 0, stream>>>(
        Wv, Wqkvt, KVh * HD, DMD, Hh * HD + KVh * HD);
    cvtT_kernel<<<dim3(DMD / 32, DMD / 32), blk, 0, stream>>>(
        Wo, Wot, DMD, DMD, 0);

    // Fused QKV projection (bf16 in, bf16 staged out; V transposed +bias).
    gemm_bt<0><<<dim3(3072 / 128, M / 128), blk, 0, stream>>>(
        Abf, Wqkvt, bv, QO, Kb, Vt, nullptr, M, 3072, DMD);

    // RoPE (in place; Q gets the 1/sqrt(HD) softmax scale folded in)
    int totq = M * Hh * 32, totk = M * KVh * 32;
    rope_kernel<<<(totq + 255) / 256, blk, 0, stream>>>(QO, cosb, sinb, Hh, totq, 0.125f);
    rope_kernel<<<(totk + 255) / 256, blk, 0, stream>>>(Kb, cosb, sinb, KVh, totk, 1.0f);

    // Flash attention v2 (O overwrites Q in place); 512 blocks, kvh = bid%8.
    fattn_kernel<<<dim3(512), blk, 0, stream>>>(QO, Kb, Vt, mask);

    // Output projection (+bias, fp32 out)
    gemm_bt<1><<<dim3(DMD / 128, M / 128), blk, 0, stream>>>(
        QO, Wot, bo, nullptr, nullptr, nullptr, out, M, DMD, DMD);
}

// Round 3
// 411.400 us; speedup vs baseline: 1.6606x; 1.0611x over previous
//
#include <hip/hip_runtime.h>
#include <hip/hip_bf16.h>

// Problem constants
#define Bb 2
#define Ss 2048
#define DMD 2048
#define Hh 32
#define KVh 8
#define HD 64
// GQA groups = H/KV = 4. Inputs/outputs fp32.

using bf16 = __hip_bfloat16;
typedef __attribute__((ext_vector_type(8))) short short8;
typedef __attribute__((ext_vector_type(4))) float floatx4;

__device__ inline float tof(const bf16 x) { return __bfloat162float(x); }
__device__ inline void stor(float* p, float v) { *p = v; }
__device__ inline void stor(bf16* p, float v) { *p = __float2bfloat16(v); }
__device__ inline short bf16bits(float v) {
    union { bf16 h; short s; } cv; cv.h = __float2bfloat16(v); return cv.s;
}

// global->LDS direct copy, 16 B per lane. LDS destination is the wave-uniform
// base; HW adds lane*16. (guide §5: width=16 is the 874-TF m97 staging path)
__device__ inline void gl_lds16(const bf16* g, bf16* l) {
    __builtin_amdgcn_global_load_lds(
        (const __attribute__((address_space(1))) unsigned int*)g,
        (__attribute__((address_space(3))) unsigned int*)l, 16, 0, 0);
}

// ---------------------------------------------------------------------------
// Prep pass 1: fp32 -> bf16 elementwise (8 elems/thread, float4 loads).
// ---------------------------------------------------------------------------
__global__ __launch_bounds__(256) void cvt_bf16_kernel(
    const float* __restrict__ in, bf16* __restrict__ out, int total8)
{
    const int i = blockIdx.x * 256 + threadIdx.x;
    if (i >= total8) return;
    const float4 a = ((const float4*)in)[2 * i];
    const float4 b = ((const float4*)in)[2 * i + 1];
    short8 r;
    r[0] = bf16bits(a.x); r[1] = bf16bits(a.y); r[2] = bf16bits(a.z); r[3] = bf16bits(a.w);
    r[4] = bf16bits(b.x); r[5] = bf16bits(b.y); r[6] = bf16bits(b.z); r[7] = bf16bits(b.w);
    ((short8*)out)[i] = r;
}

// ---------------------------------------------------------------------------
// Prep pass 2: W [K][N] fp32 -> Wt [rowOff+N][K] bf16 (transpose-convert),
// 32x32 LDS tile, 256 threads.
// ---------------------------------------------------------------------------
__global__ __launch_bounds__(256) void cvtT_kernel(
    const float* __restrict__ W, bf16* __restrict__ Wt,
    int N, int K, int rowOff)
{
    __shared__ float t[32][33];
    const int n0 = blockIdx.x * 32;
    const int k0 = blockIdx.y * 32;
    const int tx = threadIdx.x & 31, ty = threadIdx.x >> 5;   // ty 0..7
    #pragma unroll
    for (int r = 0; r < 32; r += 8)
        t[ty + r][tx] = W[(size_t)(k0 + ty + r) * N + n0 + tx];
    __syncthreads();
    #pragma unroll
    for (int r = 0; r < 32; r += 8)
        Wt[(size_t)(rowOff + n0 + ty + r) * K + k0 + tx] =
            __float2bfloat16(t[tx][ty + r]);
}

// ---------------------------------------------------------------------------
// MFMA GEMM, m97 structure: A [M][K] bf16 row-major, Bt [N][K] bf16 K-major.
// 128x128 tile, BK=32, 4 waves x (4x4 16x16x32 tiles), global_load_lds
// width-16 staging into linear [128][32] LDS tiles, 2-barrier loop.
// EPI 0: fused QKV scatter  (cols [0,2048)->Yq, [2048,2560)->Yk,
//        [2560,3072)->Yv transposed [b][kvh][d][s] with +bias)
// EPI 1: fp32 out + bias (O projection)
// ---------------------------------------------------------------------------
template <int EPI>
__global__ __launch_bounds__(256) void gemm_bt(
    const bf16* __restrict__ A, const bf16* __restrict__ Bt,
    const float* __restrict__ bias,
    bf16* __restrict__ Yq, bf16* __restrict__ Yk, bf16* __restrict__ Yv,
    float* __restrict__ Yo, int M, int N, int K)
{
    __shared__ bf16 As[128 * 32];   // [m][k] row-major, chunk ch <-> bytes ch*16
    __shared__ bf16 Bs[128 * 32];   // [n][k] row-major

    const int tid  = threadIdx.x;
    const int wave = tid >> 6, lane = tid & 63;
    const int lid  = lane & 15, quad = lane >> 4;
    const int wr = (wave >> 1) * 64, wc = (wave & 1) * 64;
    const size_t bm = (size_t)blockIdx.y * 128, bn = (size_t)blockIdx.x * 128;

    floatx4 acc[4][4];
    #pragma unroll
    for (int i = 0; i < 4; ++i)
        #pragma unroll
        for (int j = 0; j < 4; ++j)
            acc[i][j] = (floatx4){0.f, 0.f, 0.f, 0.f};

    for (int k0 = 0; k0 < K; k0 += 32) {
        // stage A-tile and B-tile: 512 16B-chunks each; wave covers 128
        // chunks (2 issues). chunk c: row = c>>2, k-col = (c&3)*8.
        #pragma unroll
        for (int i = 0; i < 2; ++i) {
            const int c   = wave * 128 + i * 64 + lane;
            const int row = c >> 2, col = (c & 3) * 8;
            gl_lds16(A  + (bm + row) * (size_t)K + k0 + col,
                     &As[(wave * 128 + i * 64) * 8]);
            gl_lds16(Bt + (bn + row) * (size_t)K + k0 + col,
                     &Bs[(wave * 128 + i * 64) * 8]);
        }
        __syncthreads();

        short8 af[4], bfr[4];
        #pragma unroll
        for (int i = 0; i < 4; ++i)
            af[i] = *(const short8*)&As[(wr + i * 16 + lid) * 32 + quad * 8];
        #pragma unroll
        for (int j = 0; j < 4; ++j)
            bfr[j] = *(const short8*)&Bs[(wc + j * 16 + lid) * 32 + quad * 8];
        #pragma unroll
        for (int i = 0; i < 4; ++i)
            #pragma unroll
            for (int j = 0; j < 4; ++j)
                acc[i][j] = __builtin_amdgcn_mfma_f32_16x16x32_bf16(
                    af[i], bfr[j], acc[i][j], 0, 0, 0);
        __syncthreads();
    }

    #pragma unroll
    for (int i = 0; i < 4; ++i) {
        const int gm0 = (int)bm + wr + i * 16 + quad * 4;
        #pragma unroll
        for (int j = 0; j < 4; ++j) {
            const int gn = (int)bn + wc + j * 16 + lid;
            #pragma unroll
            for (int r = 0; r < 4; ++r) {
                float v = acc[i][j][r];
                const int gm = gm0 + r;
                if (EPI == 0) {
                    if (gn < Hh * HD) {
                        stor(&Yq[(size_t)gm * (Hh * HD) + gn], v);
                    } else if (gn < Hh * HD + KVh * HD) {
                        stor(&Yk[(size_t)gm * (KVh * HD) + (gn - Hh * HD)], v);
                    } else {
                        const int c = gn - (Hh * HD + KVh * HD);
                        v += bias[c];
                        const int kvh = c >> 6, dd = c & 63;
                        const int bbi = gm >> 11, s = gm & (Ss - 1);
                        stor(&Yv[(((size_t)bbi * KVh + kvh) * HD + dd) * Ss + s], v);
                    }
                } else {
                    Yo[(size_t)gm * N + gn] = v + bias[gn];
                }
            }
        }
    }
}

// ---------------------------------------------------------------------------
// In-place RoPE on bf16 buf laid out [B*S][nheads][64]; fp32 cos/sin.
// scale: extra output multiplier (1/sqrt(HD) folded into Q).
// ---------------------------------------------------------------------------
__global__ void rope_kernel(bf16* __restrict__ buf,
                            const float* __restrict__ cosb,
                            const float* __restrict__ sinb,
                            int nheads, int total, float scale)
{
    int idx = blockIdx.x * blockDim.x + threadIdx.x;
    if (idx >= total) return;
    int d = idx & 31;
    int h = (idx >> 5) % nheads;
    int bs = idx / (32 * nheads);
    bf16* row = buf + ((size_t)bs * nheads + h) * HD;
    float x1 = tof(row[d]), x2 = tof(row[d + 32]);
    float c1 = cosb[(size_t)bs * HD + d];
    float s1 = sinb[(size_t)bs * HD + d];
    float c2 = cosb[(size_t)bs * HD + d + 32];
    float s2 = sinb[(size_t)bs * HD + d + 32];
    stor(&row[d],      (x1 * c1 - x2 * s1) * scale);
    stor(&row[d + 32], (x2 * c2 + x1 * s2) * scale);
}

// ---------------------------------------------------------------------------
// MFMA flash attention v3: barrier-free, direct-global K/V fragment reads,
// one 32-row q-block per WAVE (4096 waves / 1024 blocks -> ~16 waves/CU,
// double v2's occupancy). Blocks launch heavy-first (qb descending); the 4
// waves in a block differ by <=2 k-tiles, and the scheduler backfills light
// blocks into CUs that finish early. Causal masking is applied only on the
// single boundary tile; full tiles check attention_mask only. s_setprio(1)
// wraps the MFMA clusters (independent waves -> scheduler arbitration pays,
// m191). kvh = bid%8 pins each KV-head's L2 set to one XCD.
// ---------------------------------------------------------------------------
template <bool CAUSAL>
__device__ inline void fattn_tile(
    const int k0, const int m0,
    const bf16* __restrict__ kBase, const bf16* __restrict__ vBase,
    const int* __restrict__ mBase,
    const short8 qf0[2], const short8 qf1[2],
    floatx4 o[2][4], float lsum[2][4],
    short (*pw)[16][72],               // -> pLds[wave]: [2][16][72]
    const int lid, const int quad)
{
    const size_t kStride = (size_t)KVh * HD;  // 512 elems

    // ---- K fragments + S = Q K^T ----
    short8 kb0[4], kb1[4];
    #pragma unroll
    for (int nt = 0; nt < 4; ++nt) {
        const bf16* kr = kBase + (size_t)(k0 + nt * 16 + lid) * kStride + quad * 8;
        kb0[nt] = *(const short8*)(kr);
        kb1[nt] = *(const short8*)(kr + 32);
    }
    floatx4 s[2][4];
    __builtin_amdgcn_s_setprio(1);
    #pragma unroll
    for (int nt = 0; nt < 4; ++nt)
        #pragma unroll
        for (int g = 0; g < 2; ++g) {
            floatx4 c = (floatx4){0.f, 0.f, 0.f, 0.f};
            c = __builtin_amdgcn_mfma_f32_16x16x32_bf16(qf0[g], kb0[nt], c, 0, 0, 0);
            c = __builtin_amdgcn_mfma_f32_16x16x32_bf16(qf1[g], kb1[nt], c, 0, 0, 0);
            s[g][nt] = c;
        }
    __builtin_amdgcn_s_setprio(0);

    // ---- V fragment loads issue here; latency hides under softmax ----
    short8 vb0[4], vb1[4];
    #pragma unroll
    for (int nt = 0; nt < 4; ++nt) {
        const bf16* vr = vBase + (size_t)(nt * 16 + lid) * Ss + k0 + quad * 8;
        vb0[nt] = *(const short8*)(vr);
        vb1[nt] = *(const short8*)(vr + 32);
    }

    // ---- mask + exp; per-lane row-sum partials ----
    #pragma unroll
    for (int nt = 0; nt < 4; ++nt) {
        const int col = k0 + nt * 16 + lid;
        const int mk  = mBase[col];
        #pragma unroll
        for (int g = 0; g < 2; ++g) {
            const int mr0 = m0 + g * 16 + quad * 4;
            #pragma unroll
            for (int rr = 0; rr < 4; ++rr) {
                float p;
                if (CAUSAL)
                    p = (mk == 0 || col > mr0 + rr) ? 0.f : __expf(s[g][nt][rr]);
                else
                    p = (mk == 0) ? 0.f : __expf(s[g][nt][rr]);
                s[g][nt][rr] = p;
                lsum[g][rr] += p;
            }
        }
    }

    // ---- P: C-layout -> A-layout via per-wave private LDS ----
    #pragma unroll
    for (int g = 0; g < 2; ++g)
        #pragma unroll
        for (int nt = 0; nt < 4; ++nt)
            #pragma unroll
            for (int rr = 0; rr < 4; ++rr)
                pw[g][quad * 4 + rr][nt * 16 + lid] = bf16bits(s[g][nt][rr]);
    short8 pf0[2], pf1[2];
    #pragma unroll
    for (int g = 0; g < 2; ++g) {
        pf0[g] = *(const short8*)&pw[g][lid][quad * 8];
        pf1[g] = *(const short8*)&pw[g][lid][32 + quad * 8];
    }

    // ---- O += P V ----
    __builtin_amdgcn_s_setprio(1);
    #pragma unroll
    for (int nt = 0; nt < 4; ++nt)
        #pragma unroll
        for (int g = 0; g < 2; ++g) {
            o[g][nt] = __builtin_amdgcn_mfma_f32_16x16x32_bf16(
                pf0[g], vb0[nt], o[g][nt], 0, 0, 0);
            o[g][nt] = __builtin_amdgcn_mfma_f32_16x16x32_bf16(
                pf1[g], vb1[nt], o[g][nt], 0, 0, 0);
        }
    __builtin_amdgcn_s_setprio(0);
}

__global__ __launch_bounds__(256) void fattn_kernel(
    bf16* __restrict__ QO, const bf16* __restrict__ Kb,
    const bf16* __restrict__ Vt, const int* __restrict__ mask)
{
    const int bid    = blockIdx.x;      // 0..1023
    const int kvh    = bid & 7;         // XCD-local K/V reuse
    const int rest   = bid >> 3;        // 0..127
    const int qbslot = rest >> 3;       // 0..15, 0 launches first
    const int bh     = rest & 7;
    const int hg     = bh & 3;
    const int b      = bh >> 2;
    const int qb     = 15 - qbslot;     // heavy q-superblocks first
    const int h      = kvh * 4 + hg;

    const int tid  = threadIdx.x;
    const int wave = tid >> 6;
    const int lane = tid & 63;
    const int lid  = lane & 15;
    const int quad = lane >> 4;

    const int qw = qb * 4 + wave;       // 0..63, this wave's 32-row q-block
    const int m0 = qw * 32;
    const int nfull = qw >> 1;          // fully-causal-valid 64-key tiles

    __shared__ short pLds[4][2][16][72];   // per-wave private P transpose

    const size_t kStride = (size_t)KVh * HD;  // 512 elems
    const bf16* kBase = Kb + ((size_t)b * Ss) * kStride + (size_t)kvh * HD;
    const bf16* vBase = Vt + ((size_t)(b * KVh + kvh) * HD) * Ss;
    const int*  mBase = mask + b * Ss;

    // Q fragments for both 16-row groups (pre-scaled by 1/8 in rope)
    short8 qf0[2], qf1[2];
    #pragma unroll
    for (int g = 0; g < 2; ++g) {
        const bf16* qb_ = QO + ((size_t)(b * Ss + m0 + g * 16 + lid) * Hh + h) * HD
                        + quad * 8;
        qf0[g] = *(const short8*)(qb_);
        qf1[g] = *(const short8*)(qb_ + 32);
    }

    floatx4 o[2][4];
    float lsum[2][4];
    #pragma unroll
    for (int g = 0; g < 2; ++g) {
        #pragma unroll
        for (int nt = 0; nt < 4; ++nt) o[g][nt] = (floatx4){0.f, 0.f, 0.f, 0.f};
        #pragma unroll
        for (int rr = 0; rr < 4; ++rr) lsum[g][rr] = 0.f;
    }

    // Full tiles: attention_mask check only.
    for (int kt = 0; kt < nfull; ++kt)
        fattn_tile<false>(kt * 64, m0, kBase, vBase, mBase,
                          qf0, qf1, o, lsum, pLds[wave], lid, quad);
    // Boundary tile: causal + attention_mask.
    fattn_tile<true>(nfull * 64, m0, kBase, vBase, mBase,
                     qf0, qf1, o, lsum, pLds[wave], lid, quad);

    // ---- epilogue: reduce l across the 16 key-lanes, normalize, store ----
    #pragma unroll
    for (int g = 0; g < 2; ++g)
        #pragma unroll
        for (int rr = 0; rr < 4; ++rr) {
            float rs = lsum[g][rr];
            rs += __shfl_xor(rs, 1);
            rs += __shfl_xor(rs, 2);
            rs += __shfl_xor(rs, 4);
            rs += __shfl_xor(rs, 8);
            const float inv = 1.f / rs;
            const int m = m0 + g * 16 + quad * 4 + rr;
            bf16* orow = QO + ((size_t)(b * Ss + m) * Hh + h) * HD;
            #pragma unroll
            for (int nt = 0; nt < 4; ++nt)
                stor(&orow[nt * 16 + lid], o[g][nt][rr] * inv);
        }
}

// ---------------------------------------------------------------------------
extern "C" void kernel_launch(void* const* d_in, const int* in_sizes, int n_in,
                              void* d_out, int out_size, void* d_ws, size_t ws_size,
                              hipStream_t stream)
{
    const float* hs   = (const float*)d_in[0];
    const int*   mask = (const int*)d_in[1];
    const float* cosb = (const float*)d_in[2];
    const float* sinb = (const float*)d_in[3];
    const float* Wq   = (const float*)d_in[4];
    const float* Wk   = (const float*)d_in[5];
    const float* Wv   = (const float*)d_in[6];
    const float* bv   = (const float*)d_in[7];
    const float* Wo   = (const float*)d_in[8];
    const float* bo   = (const float*)d_in[9];
    float* out = (float*)d_out;

    const int M = Bb * Ss;  // 4096

    // Workspace (37.75 MB): QO bf16 [M][2048] (16.8 MB) + Wqkv_t bf16
    // [3072][2048] (12.6 MB) + Wo_t bf16 [2048][2048] (8.4 MB).
    bf16* QO    = (bf16*)d_ws;
    bf16* Wqkvt = QO + (size_t)M * (Hh * HD);
    bf16* Wot   = Wqkvt + (size_t)3072 * DMD;

    // d_out scratch (25.2 MB of 33.5 MB): Kb, Vt (front), Abf (middle).
    // All three are dead before the O-projection overwrites d_out.
    bf16* Kb  = (bf16*)d_out;
    bf16* Vt  = Kb + (size_t)M * (KVh * HD);
    bf16* Abf = Vt + (size_t)M * (KVh * HD);

    dim3 blk(256);

    // Prep: hs -> bf16; weights -> K-major bf16 (Wq|Wk|Wv concatenated).
    const int total8 = M * DMD / 8;
    cvt_bf16_kernel<<<(total8 + 255) / 256, blk, 0, stream>>>(hs, Abf, total8);
    cvtT_kernel<<<dim3((Hh * HD) / 32, DMD / 32), blk, 0, stream>>>(
        Wq, Wqkvt, Hh * HD, DMD, 0);
    cvtT_kernel<<<dim3((KVh * HD) / 32, DMD / 32), blk, 0, stream>>>(
        Wk, Wqkvt, KVh * HD, DMD, Hh * HD);
    cvtT_kernel<<<dim3((KVh * HD) / 32, DMD / 32), blk, 0, stream>>>(
        Wv, Wqkvt, KVh * HD, DMD, Hh * HD + KVh * HD);
    cvtT_kernel<<<dim3(DMD / 32, DMD / 32), blk, 0, stream>>>(
        Wo, Wot, DMD, DMD, 0);

    // Fused QKV projection (bf16 in, bf16 staged out; V transposed +bias).
    gemm_bt<0><<<dim3(3072 / 128, M / 128), blk, 0, stream>>>(
        Abf, Wqkvt, bv, QO, Kb, Vt, nullptr, M, 3072, DMD);

    // RoPE (in place; Q gets the 1/sqrt(HD) softmax scale folded in)
    int totq = M * Hh * 32, totk = M * KVh * 32;
    rope_kernel<<<(totq + 255) / 256, blk, 0, stream>>>(QO, cosb, sinb, Hh, totq, 0.125f);
    rope_kernel<<<(totk + 255) / 256, blk, 0, stream>>>(Kb, cosb, sinb, KVh, totk, 1.0f);

    // Flash attention v3 (O overwrites Q in place); 1024 blocks, 1 q-block/wave.
    fattn_kernel<<<dim3(1024), blk, 0, stream>>>(QO, Kb, Vt, mask);

    // Output projection (+bias, fp32 out)
    gemm_bt<1><<<dim3(DMD / 128, M / 128), blk, 0, stream>>>(
        QO, Wot, bo, nullptr, nullptr, nullptr, out, M, DMD, DMD);
}